// Round 5
// baseline (192.833 us; speedup 1.0000x reference)
//
#include <hip/hip_runtime.h>

#define LTAG 64
#define NEGV -10000.0f
#define L2E 1.4426950408889634f
#define LN2 0.6931471805599453f

typedef float vfloat2 __attribute__((ext_vector_type(2)));

// v_exp_f32: 2^x ; v_log_f32: log2(x)
__device__ __forceinline__ float exp2_fast(float x) { return __builtin_amdgcn_exp2f(x); }
__device__ __forceinline__ float log2_fast(float x) { return __builtin_amdgcn_logf(x); }

__device__ __forceinline__ float readlane_f(float v, int lane) {
    return __int_as_float(__builtin_amdgcn_readlane(__float_as_int(v), lane));
}

// One wave (64 lanes) per batch element. lane = next-tag index n.
//
// Exp-domain recurrence: state A[n] = exp2(alpha[n]*L2E - SH), SH wave-uniform.
//   A'[n] = (sum_p A[p] * Etr[p][n]) * g[n],  g[n] = exp2(x_t[n]*L2E + c2[n])
// with Etr[p][n] = exp2(trans[p][n]*L2E - c2[n]) constant in VGPRs.
//
// ROUND-5 STRUCTURE — dual-pipe broadcast. Round-4 counters showed the wave
// is ISSUE-bound on its single SIMD (VALUBusy 17.3% of a 25% one-SIMD
// ceiling = ~69% issue-busy; 64 readlane ~4cy each + 64 fmac dominate). So:
//   p = 0..31  : batched v_readlane -> 32 SGPRs, then 32 v_fmac
//                (separate loops => no SGPR-write hazards; round-4 proven)
//   p = 32..63 : DS pipe — ds_write(A) at step end, 8 uniform ds_read_b128
//                at step start (bank-conflict-free broadcast), consumed by
//                16 v_pk_fma_f32. ~130cy LDS latency hides under the ~190cy
//                readlane/fmac phase, which is independent of it.
// This moves ~32 readlanes (~128cy) + 32 fmacs (~64cy) off the VALU issue
// stream at a cost of ~24cy DS issue + 32cy pk_fma.
//   - g's exp2 is per-substep from a distance-4 prefetch ring (round-2
//     lesson: never consume a load issued <4 steps ago).
//   - single wave per block + in-order same-wave DS pipe => NO barriers.
//   - main loop peeled from tail group: no clamp cmp/cndmask in the hot
//     loop; tail group issues no prefetch.
//
// Exact power-of-2 rescale every 4 steps keeps A in fp32 range (growth
// <~2^19/step worst case; sampled-max spread ~2^35; 35+4*19 < 127).
//
// Column B (lane 0) is fully masked (-10000): g[B] == 0 exactly, so A[B] == 0
// throughout. Its true final value is recovered analytically: lane 0's Etr
// column is all-ones (c2_B = -10000*L2E), so its per-step matvec result
// s_B = sum_p A[p]; the last step's (s, x, SH) give
// alpha_T[B] = (log2 s_B + x*L2E + c2_B + SH)*LN2.
__global__ __launch_bounds__(64) void crf_forward_kernel(
    const float* __restrict__ X, const float* __restrict__ trans,
    float* __restrict__ out, int T) {
    const int lane = threadIdx.x;
    const int b = blockIdx.x;
    const float* xb = X + (size_t)b * T * LTAG + lane;

    __shared__ __align__(16) float e_sh[LTAG];

    // ---- precompute Etr column for this lane (once) ----
    // lower half (p=0..31): scalar floats (v_fmac with SGPR broadcast)
    // upper half (p=32..63): float2 pairs (v_pk_fma_f32 against LDS reads)
    float etrL[32];
    vfloat2 etrH[16];
    float c2 = -3.0e38f;
#pragma unroll
    for (int p = 0; p < 32; ++p) {
        etrL[p] = trans[p * LTAG + lane] * L2E;
        c2 = fmaxf(c2, etrL[p]);
    }
#pragma unroll
    for (int i = 0; i < 16; ++i) {
        const float t0 = trans[(32 + 2 * i) * LTAG + lane] * L2E;
        const float t1 = trans[(33 + 2 * i) * LTAG + lane] * L2E;
        c2 = fmaxf(c2, fmaxf(t0, t1));
        etrH[i].x = t0;
        etrH[i].y = t1;
    }
#pragma unroll
    for (int p = 0; p < 32; ++p) etrL[p] = exp2_fast(etrL[p] - c2);
#pragma unroll
    for (int i = 0; i < 16; ++i) {
        etrH[i].x = exp2_fast(etrH[i].x - c2);
        etrH[i].y = exp2_fast(etrH[i].y - c2);
    }

    // ---- init: alpha = NEG except tag B (lane 0) = 0 ----
    float A = (lane == 0) ? 1.0f : 0.0f;
    float SH = 0.0f;
    float sB = 1.0f, xB = 0.0f, shB = 0.0f;  // lane-0 (tag B) fixup state

    // ---- x prefetch ring, distance 4 ----
    float xr[4];
#pragma unroll
    for (int i = 0; i < 4; ++i) xr[i] = xb[(size_t)i * LTAG];

    e_sh[lane] = A;  // prologue ds_write (same-wave order covers first reads)

// one recurrence substep; PF_STMT reloads xr[u] (empty in the tail group)
#define SUBSTEP(u, PF_STMT)                                                   \
    {                                                                         \
        const float xcur = xr[u];                                             \
        PF_STMT;                                                              \
        /* off the serial chain: exp2 latency hides under the matvec */       \
        const float g = exp2_fast(fmaf(xcur, L2E, c2));                       \
        /* upper-half uniform LDS broadcast reads, issued EARLY */            \
        float4 ev[8];                                                         \
        _Pragma("unroll") for (int i = 0; i < 8; ++i)                         \
            ev[i] = *(const float4*)(e_sh + 32 + 4 * i);                      \
        /* lower half: batched readlanes, then fmacs (4 chains) */            \
        float ub[32];                                                         \
        _Pragma("unroll") for (int p = 0; p < 32; ++p)                        \
            ub[p] = readlane_f(A, p);                                         \
        float s0 = 0.f, s1 = 0.f, s2 = 0.f, s3 = 0.f;                         \
        _Pragma("unroll") for (int p = 0; p < 32; p += 4) {                   \
            s0 = fmaf(ub[p + 0], etrL[p + 0], s0);                            \
            s1 = fmaf(ub[p + 1], etrL[p + 1], s1);                            \
            s2 = fmaf(ub[p + 2], etrL[p + 2], s2);                            \
            s3 = fmaf(ub[p + 3], etrL[p + 3], s3);                            \
        }                                                                     \
        /* upper half: packed fma against LDS broadcast */                    \
        vfloat2 h0 = {0.f, 0.f}, h1 = {0.f, 0.f};                             \
        _Pragma("unroll") for (int i = 0; i < 8; ++i) {                       \
            const vfloat2 ea = {ev[i].x, ev[i].y};                            \
            const vfloat2 eb = {ev[i].z, ev[i].w};                            \
            h0 = __builtin_elementwise_fma(ea, etrH[2 * i + 0], h0);          \
            h1 = __builtin_elementwise_fma(eb, etrH[2 * i + 1], h1);          \
        }                                                                     \
        const vfloat2 hh = h0 + h1;                                           \
        const float s = ((s0 + s1) + (s2 + s3)) + (hh.x + hh.y);              \
        sB = s; xB = xcur; shB = SH; /* last-step save for lane-0 fixup */    \
        A = s * g;                                                            \
        if (u == 3) {                                                         \
            /* wave-uniform EXACT power-of-2 rescale, every 4 steps; */       \
            /* samples avoid lane 0 (tag B: exactly 0 in exp domain) */       \
            float mm = fmaxf(readlane_f(A, 2), readlane_f(A, 19));            \
            mm = fmaxf(mm, readlane_f(A, 28));                                \
            mm = fmaxf(mm, fmaxf(readlane_f(A, 37), readlane_f(A, 53)));      \
            int eb2 = (__float_as_int(mm) >> 23) & 0xff;                      \
            eb2 = eb2 < 1 ? 1 : eb2;                                          \
            A *= __int_as_float((254 - eb2) << 23); /* *=2^(127-eb), exact */ \
            SH += (float)(eb2 - 127);                                         \
        }                                                                     \
        e_sh[lane] = A; /* ds_write for NEXT substep's upper half */          \
    }

    // main loop: all prefetch indices t+u+4 <= T-1 (no clamp needed)
    const float* xp = xb + 4 * (size_t)LTAG;
    int t = 0;
    for (; t + 8 <= T; t += 4) {
        SUBSTEP(0, xr[0] = xp[0 * LTAG]);
        SUBSTEP(1, xr[1] = xp[1 * LTAG]);
        SUBSTEP(2, xr[2] = xp[2 * LTAG]);
        SUBSTEP(3, xr[3] = xp[3 * LTAG]);
        xp += 4 * LTAG;
    }
    // tail group (t = T-4 when T%4==0): no prefetch
    for (; t < T; t += 4) {
        SUBSTEP(0, );
        SUBSTEP(1, );
        SUBSTEP(2, );
        SUBSTEP(3, );
    }
#undef SUBSTEP

    float res;
    if (lane == 0) {
        // tag B analytic fixup (see header comment)
        res = (log2_fast(sB) + fmaf(xB, L2E, c2) + shB) * LN2;
    } else {
        res = (log2_fast(A) + SH) * LN2;
    }
    out[b * LTAG + lane] = res;
}

extern "C" void kernel_launch(void* const* d_in, const int* in_sizes, int n_in,
                              void* d_out, int out_size, void* d_ws, size_t ws_size,
                              hipStream_t stream) {
    const float* X = (const float*)d_in[0];
    const float* trans = (const float*)d_in[1];
    float* out = (float*)d_out;

    const int B = out_size / LTAG;           // 256
    const int T = in_sizes[0] / (B * LTAG);  // 512

    crf_forward_kernel<<<B, LTAG, 0, stream>>>(X, trans, out, T);
}

// Round 6
// 177.066 us; speedup vs baseline: 1.0890x; 1.0890x over previous
//
#include <hip/hip_runtime.h>

#define LTAG 64
#define WAVES 4
#define L2E 1.4426950408889634f
#define LN2 0.6931471805599453f

// v_exp_f32: 2^x ; v_log_f32: log2(x)
__device__ __forceinline__ float exp2_fast(float x) { return __builtin_amdgcn_exp2f(x); }
__device__ __forceinline__ float log2_fast(float x) { return __builtin_amdgcn_logf(x); }

__device__ __forceinline__ float readlane_f(float v, int lane) {
    return __int_as_float(__builtin_amdgcn_readlane(__float_as_int(v), lane));
}

// ROUND-6 STRUCTURE — 4 cooperative waves per batch element (256 thr/block),
// one block per CU: puts all 4 SIMDs on the serial chain instead of 1.
//
// Exp-domain recurrence: state A[n] = exp2(alpha[n]*L2E - SH), SH wave-uniform.
//   A'[n] = (sum_p A[p] * Etr[p][n]) * g[n],  g[n] = exp2(x_t[n]*L2E + c2[n])
//
// Every wave keeps the FULL A vector in its lanes (lane n <-> A[n]) and
// redundantly computes the identical A' each step — so the all-to-all
// broadcast of A disappears entirely. Per step, wave w:
//   - 16 batched v_readlane of its own A copy (p = 16w..16w+15), 16 v_fmac
//     -> one partial per lane                      (issue ~100 cy, 1 SIMD)
//   - ds_write partial; raw barrier; 4 conflict-free ds_read_b32 (partials
//     of all 4 waves); 3 adds; * g  ->  new A      (~180 cy latency)
// Serial chain ~300 cy/step vs ~600 for any single-wave variant (rounds 3-5
// showed one wave is issue-bound at ~410 cy OR LDS-latency-bound at ~500+).
//
// CRITICAL: __syncthreads() would emit s_waitcnt vmcnt(0) before s_barrier,
// stalling every step on the in-flight x prefetch (HBM ~900 cy). We need
// write-visibility only, so: s_waitcnt lgkmcnt(0) + s_barrier via inline asm
// — global loads stay in flight across the barrier. Double-buffered partials
// make one barrier per step sufficient (reads of buf are data-consumed before
// the next barrier; the conflicting rewrite of buf is two barriers away).
//
// g's exp2 is per-substep from a distance-4 prefetch ring (round-2 lesson).
// Exact power-of-2 rescale every 4 steps (growth <2^19/step, spread ~2^35;
// 35+4*19 < 127), identical in all waves (same A, same deterministic ops).
//
// Column B (lane 0) fully masked (-10000): g[B]==0 exactly -> A[B]==0
// throughout; final value recovered analytically from the last step's
// s (lane 0's Etr column is all-ones after c2 normalization): 
// alpha_T[B] = (log2 s_B + x*L2E + c2_B + SH)*LN2.
__global__ __launch_bounds__(WAVES * 64) void crf_forward_kernel(
    const float* __restrict__ X, const float* __restrict__ trans,
    float* __restrict__ out, int T) {
    const int tid = threadIdx.x;
    const int lane = tid & 63;
    const int wid = __builtin_amdgcn_readfirstlane(tid >> 6);  // SGPR, uniform/wave
    const int b = blockIdx.x;
    const float* xb = X + (size_t)b * T * LTAG + lane;

    __shared__ __align__(16) float part[2][WAVES * LTAG];

    // ---- per-lane column max over ALL p, + this wave's 16 Etr entries ----
    float c2 = -3.0e38f;
#pragma unroll
    for (int p = 0; p < LTAG; ++p) c2 = fmaxf(c2, trans[p * LTAG + lane] * L2E);
    float etr16[16];
#pragma unroll
    for (int i = 0; i < 16; ++i)
        etr16[i] = exp2_fast(trans[(wid * 16 + i) * LTAG + lane] * L2E - c2);

    // ---- init: alpha = NEG except tag B (lane 0) = 0 ----
    float A = (lane == 0) ? 1.0f : 0.0f;
    float SH = 0.0f;
    float sB = 1.0f, xB = 0.0f, shB = 0.0f;  // lane-0 (tag B) fixup state

    // ---- x prefetch ring, distance 4 (per wave; L1 dedups across waves) --
    float xr[4];
#pragma unroll
    for (int i = 0; i < 4; ++i) xr[i] = xb[(size_t)i * LTAG];

    const int pbase = wid * 16;
    int buf = 0;

// one recurrence substep; PF_STMT reloads xr[u] (empty in the tail group)
#define SUBSTEP(u, PF_STMT)                                                   \
    {                                                                         \
        const float xcur = xr[u];                                             \
        PF_STMT;                                                              \
        /* off the serial chain: exp2 latency hides under the partial */      \
        const float g = exp2_fast(fmaf(xcur, L2E, c2));                       \
        /* this wave's 16 p's: batched readlanes, then fmacs (4 chains) */    \
        float ub[16];                                                         \
        _Pragma("unroll") for (int i = 0; i < 16; ++i)                        \
            ub[i] = readlane_f(A, pbase + i);                                 \
        float q0 = 0.f, q1 = 0.f, q2 = 0.f, q3 = 0.f;                         \
        _Pragma("unroll") for (int i = 0; i < 16; i += 4) {                   \
            q0 = fmaf(ub[i + 0], etr16[i + 0], q0);                           \
            q1 = fmaf(ub[i + 1], etr16[i + 1], q1);                           \
            q2 = fmaf(ub[i + 2], etr16[i + 2], q2);                           \
            q3 = fmaf(ub[i + 3], etr16[i + 3], q3);                           \
        }                                                                     \
        part[buf][wid * LTAG + lane] = (q0 + q1) + (q2 + q3);                 \
        /* write-visibility barrier WITHOUT vmcnt drain (keep x in flight) */ \
        asm volatile("s_waitcnt lgkmcnt(0)\n\ts_barrier" ::: "memory");       \
        /* cross-wave combine: 4 conflict-free b32 broadcgather + 3 adds */   \
        const float s = (part[buf][lane] + part[buf][LTAG + lane]) +          \
                        (part[buf][2 * LTAG + lane] + part[buf][3 * LTAG + lane]); \
        buf ^= 1;                                                             \
        sB = s; xB = xcur; shB = SH; /* last-step save, lane-0 fixup */       \
        A = s * g;                                                            \
        if (u == 3) {                                                         \
            /* wave-uniform EXACT power-of-2 rescale, every 4 steps; */       \
            /* identical in all waves; samples avoid lane 0 (A[0]==0) */      \
            float mm = fmaxf(readlane_f(A, 2), readlane_f(A, 19));            \
            mm = fmaxf(mm, readlane_f(A, 28));                                \
            mm = fmaxf(mm, fmaxf(readlane_f(A, 37), readlane_f(A, 53)));      \
            int eb2 = (__float_as_int(mm) >> 23) & 0xff;                      \
            eb2 = eb2 < 1 ? 1 : eb2;                                          \
            A *= __int_as_float((254 - eb2) << 23); /* *=2^(127-eb), exact */ \
            SH += (float)(eb2 - 127);                                         \
        }                                                                     \
    }

    // main loop: all prefetch indices t+u+4 <= T-1 (no clamp needed)
    const float* xp = xb + 4 * (size_t)LTAG;
    int t = 0;
    for (; t + 8 <= T; t += 4) {
        SUBSTEP(0, xr[0] = xp[0 * LTAG]);
        SUBSTEP(1, xr[1] = xp[1 * LTAG]);
        SUBSTEP(2, xr[2] = xp[2 * LTAG]);
        SUBSTEP(3, xr[3] = xp[3 * LTAG]);
        xp += 4 * LTAG;
    }
    // tail group (t = T-4 when T%4==0): no prefetch
    for (; t < T; t += 4) {
        SUBSTEP(0, );
        SUBSTEP(1, );
        SUBSTEP(2, );
        SUBSTEP(3, );
    }
#undef SUBSTEP

    float res;
    if (lane == 0) {
        // tag B analytic fixup (see header comment)
        res = (log2_fast(sB) + fmaf(xB, L2E, c2) + shB) * LN2;
    } else {
        res = (log2_fast(A) + SH) * LN2;
    }
    if (wid == 0) out[b * LTAG + lane] = res;  // all waves identical; w0 writes
}

extern "C" void kernel_launch(void* const* d_in, const int* in_sizes, int n_in,
                              void* d_out, int out_size, void* d_ws, size_t ws_size,
                              hipStream_t stream) {
    const float* X = (const float*)d_in[0];
    const float* trans = (const float*)d_in[1];
    float* out = (float*)d_out;

    const int B = out_size / LTAG;           // 256
    const int T = in_sizes[0] / (B * LTAG);  // 512

    crf_forward_kernel<<<B, WAVES * 64, 0, stream>>>(X, trans, out, T);
}